// Round 9
// baseline (294.499 us; speedup 1.0000x reference)
//
#include <hip/hip_runtime.h>
#include <hip/hip_fp16.h>

// SubgraphPooling: padded-bucket scatter + fused bucket-sort/reduce (fp16).
// out[s,:] = mean over edges e with sid[e]==s of feat[nid[e],:]
// N_NODES=100000, D=128, E=2000000, N_SEG=250000
//
// R13 changes vs R12 (289us):
//  - scatter: EPB 8192->4096 (LDS 58->34KB) -> 4 blocks/CU (was 2),
//    489 blocks; barrier-phase latency was the cost (traffic is ~30MB).
//  - reduce_f: stage pairs into LDS during the count pass -> segment
//    scatter reads LDS (kills the 2nd global pass, ~15MB + a phase).
//  - memset dispatch eliminated: cvt block 0 zeros cursor/ovf_cnt
//    (stream-ordered before scatter). 3 dispatches total.

constexpr int N_NODES = 100000;
constexpr int D_FEAT  = 128;
constexpr int N_SEG   = 250000;

constexpr int BSHIFT     = 8;
constexpr int SEGS_PER_B = 1 << BSHIFT;                        // 256
constexpr int NB         = (N_SEG + SEGS_PER_B - 1) >> BSHIFT; // 977
constexpr int NB_PAD     = 1024;
constexpr int EPB        = 4096;                               // edges/block
constexpr int CTH        = 512;
constexpr int CAP_B      = 4096;                               // slots/bucket
constexpr int NID_BITS   = 17;                                 // 100000 < 2^17
constexpr int NID_MASK   = (1 << NID_BITS) - 1;
constexpr int OVF_CAP    = 262144;

// ---- workspace layout ----
// [0, 3908)        cursor[NB]          (zeroed by cvt block 0)
// [4096, 4100)     ovf_cnt             (zeroed by cvt block 0)
// [1MB, 1MB+15.3MB) pairs  int[NB*CAP_B]
// [18MB, 20MB)     ovf    int2[OVF_CAP]
// [20MB, +25.6MB)  feat16
#define NP_CUR(ws)    ((int*)((char*)(ws) + 0))
#define NP_OVFC(ws)   ((int*)((char*)(ws) + 4096))
#define NP_PAIRS(ws)  ((int*)((char*)(ws) + (1u<<20)))
#define NP_OVF(ws)    ((int2*)((char*)(ws) + (18u<<20)))
#define NP_F16(ws)    ((char*)(ws) + (20u<<20))
constexpr size_t FP16_BYTES = (size_t)N_NODES * D_FEAT * 2;          // 25.6 MB
constexpr size_t WS_NEED_H  = (size_t)(20u << 20) + FP16_BYTES;      // ~46.6 MB

// ---- fallback (verified fp32 rank path) layout ----
#define RP_CNT(ws)     ((int*)((char*)(ws) + 0))
#define RP_OFF(ws)     ((int*)((char*)(ws) + (1u<<20)))
#define RP_BSUM(ws)    ((int*)((char*)(ws) + (2u<<20)))
#define RP_RANK(ws)    ((int*)((char*)(ws) + (4u<<20)))
#define RP_SORTED(ws)  ((int*)((char*)(ws) + (12u<<20)))
constexpr int SCAN_CHUNK  = 1024;
constexpr int SCAN_BLOCKS = (N_SEG + SCAN_CHUNK - 1) / SCAN_CHUNK;  // 245

typedef float nt4 __attribute__((ext_vector_type(4)));
typedef unsigned int ntu4 __attribute__((ext_vector_type(4)));

// ================= bucket scatter (one pass, padded regions) =============

__global__ __launch_bounds__(CTH) void sp_bucket_scatter(
    const int* __restrict__ sid, const int* __restrict__ nid,
    int* __restrict__ cursor_g, int* __restrict__ pairs,
    int* __restrict__ ovf_cnt, int2* __restrict__ ovf, int n)
{
    __shared__ int hist[NB_PAD];               // counts -> LDS cursors (4KB)
    __shared__ int dstb[NB_PAD];               // global base - local off (4KB)
    __shared__ int lpair[EPB];                 // packed (slow<<17|nid), 16KB
    __shared__ unsigned short lbuck[EPB];      // bucket per slot, 8KB
    __shared__ int sh[CTH];                    // 2KB
    int tid = threadIdx.x;
    int e0  = blockIdx.x * EPB;
    int m   = min(EPB, n - e0);

    for (int i = tid; i < NB_PAD; i += CTH) hist[i] = 0;
    __syncthreads();
    for (int i = tid; i < m; i += CTH)
        atomicAdd(&hist[sid[e0 + i] >> BSHIFT], 1);
    __syncthreads();

    // exclusive scan of 1024 bucket counts (2/thread over 512 threads)
    int b0 = 2 * tid, b1 = 2 * tid + 1;
    int h0 = hist[b0], h1 = hist[b1];
    sh[tid] = h0 + h1;
    __syncthreads();
    for (int o = 1; o < CTH; o <<= 1) {
        int t = (tid >= o) ? sh[tid - o] : 0;
        __syncthreads();
        sh[tid] += t;
        __syncthreads();
    }
    int excl = (tid > 0) ? sh[tid - 1] : 0;
    __syncthreads();                           // all reads of hist done
    hist[b0] = excl;                           // LDS scatter cursors
    hist[b1] = excl + h0;
    // allocate this block's run in each bucket's padded region
    int a0 = (b0 < NB && h0 > 0) ? atomicAdd(&cursor_g[b0], h0) : 0;
    int a1 = (b1 < NB && h1 > 0) ? atomicAdd(&cursor_g[b1], h1) : 0;
    dstb[b0] = a0 - excl;
    dstb[b1] = a1 - (excl + h0);
    __syncthreads();

    // group into LDS by bucket
    for (int i = tid; i < m; i += CTH) {
        int s = sid[e0 + i], v = nid[e0 + i];
        int b = s >> BSHIFT;
        int r = atomicAdd(&hist[b], 1);
        lpair[r] = ((s & (SEGS_PER_B - 1)) << NID_BITS) | v;
        lbuck[r] = (unsigned short)b;
    }
    __syncthreads();

    // write out: each bucket's run lands contiguously in its padded region
    for (int i = tid; i < m; i += CTH) {
        int b  = lbuck[i];
        int p  = dstb[b] + i;                  // position within bucket
        int pk = lpair[i];
        if (p < CAP_B) {
            pairs[b * CAP_B + p] = pk;
        } else {                               // far-tail overflow: exact list
            int o = atomicAdd(ovf_cnt, 1);
            if (o < OVF_CAP)
                ovf[o] = make_int2((b << BSHIFT) | (pk >> NID_BITS),
                                   pk & NID_MASK);
        }
    }
}

// ================= fp16 table (+ cursor zeroing, saves a dispatch) =======

__global__ __launch_bounds__(256) void sp_cvt(
    const float* __restrict__ in, unsigned int* __restrict__ out, int n8,
    int* __restrict__ cursor_g, int* __restrict__ ovf_cnt)
{
    if (blockIdx.x == 0) {                     // stream-ordered before scatter
        for (int k = threadIdx.x; k < NB; k += 256) cursor_g[k] = 0;
        if (threadIdx.x == 0) *ovf_cnt = 0;
    }
    int i = blockIdx.x * blockDim.x + threadIdx.x;
    if (i >= n8) return;
    const nt4* in4 = (const nt4*)in;
    nt4 v0 = __builtin_nontemporal_load(&in4[2 * i + 0]);
    nt4 v1 = __builtin_nontemporal_load(&in4[2 * i + 1]);
    __half2 h0 = __floats2half2_rn(v0.x, v0.y);
    __half2 h1 = __floats2half2_rn(v0.z, v0.w);
    __half2 h2 = __floats2half2_rn(v1.x, v1.y);
    __half2 h3 = __floats2half2_rn(v1.z, v1.w);
    ntu4 o;
    o.x = *(const unsigned int*)&h0;
    o.y = *(const unsigned int*)&h1;
    o.z = *(const unsigned int*)&h2;
    o.w = *(const unsigned int*)&h3;
    __builtin_nontemporal_store(o, (ntu4*)out + i);
}

__device__ __forceinline__ float2 h2f(unsigned short lo, unsigned short hi)
{
    __half2 h = __halves2half2(__ushort_as_half(lo), __ushort_as_half(hi));
    return __half22float2(h);
}

__device__ __forceinline__ void acc_h(float4& acc, const ushort4& b)
{
    float2 f01 = h2f(b.x, b.y);
    float2 f23 = h2f(b.z, b.w);
    acc.x += f01.x; acc.y += f01.y; acc.z += f23.x; acc.w += f23.y;
}

// ============ fused bucket-sort + reduce (one block per bucket) ==========

__global__ __launch_bounds__(CTH) void sp_reduce_f(
    const ushort4* __restrict__ feat16,    // [N_NODES][32] ushort4
    const int* __restrict__ pairs,
    const int* __restrict__ cursor_g,
    const int* __restrict__ ovf_cnt,
    const int2* __restrict__ ovf,
    float4* __restrict__ out4)             // [N_SEG][32] float4
{
    __shared__ int cnt[SEGS_PER_B];
    __shared__ int beg[SEGS_PER_B];
    __shared__ int cur[SEGS_PER_B];
    __shared__ int sh[SEGS_PER_B];
    __shared__ int lp[CAP_B];              // 16KB staged pairs (1 global pass)
    __shared__ int snid[CAP_B];            // 16KB segment-sorted nids
    int B = blockIdx.x, tid = threadIdx.x;
    int total = cursor_g[B];
    int mc = min(total, CAP_B);
    const int* bp = pairs + (size_t)B * CAP_B;

    if (tid < SEGS_PER_B) cnt[tid] = 0;
    __syncthreads();
    for (int i = tid; i < mc; i += CTH) {
        int p = bp[i];
        lp[i] = p;
        atomicAdd(&cnt[(p >> NID_BITS) & (SEGS_PER_B - 1)], 1);
    }
    __syncthreads();

    int c = (tid < SEGS_PER_B) ? cnt[tid] : 0;
    if (tid < SEGS_PER_B) sh[tid] = c;
    __syncthreads();
    for (int o = 1; o < SEGS_PER_B; o <<= 1) {
        int t = (tid < SEGS_PER_B && tid >= o) ? sh[tid - o] : 0;
        __syncthreads();
        if (tid < SEGS_PER_B) sh[tid] += t;
        __syncthreads();
    }
    if (tid < SEGS_PER_B) { beg[tid] = sh[tid] - c; cur[tid] = sh[tid] - c; }
    __syncthreads();

    for (int i = tid; i < mc; i += CTH) {
        int p  = lp[i];
        int sl = (p >> NID_BITS) & (SEGS_PER_B - 1);
        int r  = atomicAdd(&cur[sl], 1);
        snid[r] = p & NID_MASK;
    }
    __syncthreads();

    int ovfB = total - mc;                 // >0 -> this bucket overflowed
    int ovn  = (ovfB > 0) ? min(*ovf_cnt, OVF_CAP) : 0;

    int hw = tid >> 5, lane = tid & 31;    // 16 half-waves x 16 segments
    for (int t = 0; t < SEGS_PER_B / 16; ++t) {
        int sl = hw * (SEGS_PER_B / 16) + t;
        int s  = (B << BSHIFT) + sl;
        if (s >= N_SEG) continue;
        int nst = cnt[sl], bg = beg[sl];
        int m2  = (nst < 32) ? nst : 32;
        int myid = (lane < m2) ? snid[bg + lane] : 0;

        float4 acc0 = make_float4(0.f, 0.f, 0.f, 0.f);
        float4 acc1 = make_float4(0.f, 0.f, 0.f, 0.f);
        if (m2 > 0) {
            int last = m2 - 1;
            for (int j0 = 0; j0 < m2; j0 += 8) {
                int id[8];
#pragma unroll
                for (int k = 0; k < 8; ++k) {
                    int jj = j0 + k;
                    id[k] = __shfl(myid, (jj < last) ? jj : last, 32);
                }
                ushort4 b[8];
#pragma unroll
                for (int k = 0; k < 8; ++k)
                    b[k] = feat16[(size_t)id[k] * 32 + lane];
#pragma unroll
                for (int k = 0; k < 8; ++k) {
                    if (j0 + k < m2) {
                        if (k & 1) acc_h(acc1, b[k]);
                        else       acc_h(acc0, b[k]);
                    }
                }
            }
            for (int k = 32; k < nst; ++k)          // n>32: LDS-resident tail
                acc_h(acc0, feat16[(size_t)snid[bg + k] * 32 + lane]);
        }
        int ntrue = nst;
        if (ovfB > 0) {                             // exact overflow drain
            for (int k = 0; k < ovn; ++k) {
                int2 e = ovf[k];
                if (e.x == s) {
                    acc_h(acc0, feat16[(size_t)e.y * 32 + lane]);
                    ++ntrue;
                }
            }
        }
        float inv = 1.0f / (float)((ntrue > 0) ? ntrue : 1);
        nt4 r;
        r.x = (acc0.x + acc1.x) * inv;
        r.y = (acc0.y + acc1.y) * inv;
        r.z = (acc0.z + acc1.z) * inv;
        r.w = (acc0.w + acc1.w) * inv;
        __builtin_nontemporal_store(
            r, reinterpret_cast<nt4*>(out4) + (size_t)s * 32 + lane);
    }
}

// ================= fallback path (verified fp32 rank path) ===============

__global__ __launch_bounds__(256) void sp_hist_rank(
    const int* __restrict__ sid, int* __restrict__ cnt,
    int* __restrict__ rank, int n)
{
    int i = blockIdx.x * blockDim.x + threadIdx.x;
    if (i >= n) return;
    int s = sid[i];
    rank[i] = atomicAdd(&cnt[s], 1);
}

__global__ __launch_bounds__(256) void sp_scan_local(
    const int* __restrict__ cnt, int* __restrict__ off, int* __restrict__ bsum)
{
    __shared__ int sh[256];
    int tid  = threadIdx.x;
    int base = blockIdx.x * SCAN_CHUNK + tid * 4;
    int v0 = (base + 0 < N_SEG) ? cnt[base + 0] : 0;
    int v1 = (base + 1 < N_SEG) ? cnt[base + 1] : 0;
    int v2 = (base + 2 < N_SEG) ? cnt[base + 2] : 0;
    int v3 = (base + 3 < N_SEG) ? cnt[base + 3] : 0;
    sh[tid] = v0 + v1 + v2 + v3;
    __syncthreads();
    for (int o = 1; o < 256; o <<= 1) {
        int t = (tid >= o) ? sh[tid - o] : 0;
        __syncthreads();
        sh[tid] += t;
        __syncthreads();
    }
    int excl = (tid > 0) ? sh[tid - 1] : 0;
    if (base + 0 < N_SEG) off[base + 0] = excl;
    if (base + 1 < N_SEG) off[base + 1] = excl + v0;
    if (base + 2 < N_SEG) off[base + 2] = excl + v0 + v1;
    if (base + 3 < N_SEG) off[base + 3] = excl + v0 + v1 + v2;
    if (tid == 255) bsum[blockIdx.x] = sh[255];
}

__global__ __launch_bounds__(256) void sp_scan_blocks(int* __restrict__ bsum)
{
    __shared__ int sh[256];
    int tid = threadIdx.x;
    int v = (tid < SCAN_BLOCKS) ? bsum[tid] : 0;
    sh[tid] = v;
    __syncthreads();
    for (int o = 1; o < 256; o <<= 1) {
        int t = (tid >= o) ? sh[tid - o] : 0;
        __syncthreads();
        sh[tid] += t;
        __syncthreads();
    }
    if (tid < SCAN_BLOCKS) bsum[tid] = sh[tid] - v;
}

__global__ __launch_bounds__(256) void sp_reorder_rank(
    const int* __restrict__ nid, const int* __restrict__ sid,
    const int* __restrict__ off, const int* __restrict__ bsum,
    const int* __restrict__ rank, int* __restrict__ sorted_nid, int n)
{
    int i = blockIdx.x * blockDim.x + threadIdx.x;
    if (i >= n) return;
    int s = sid[i];
    sorted_nid[off[s] + bsum[s >> 10] + rank[i]] = nid[i];
}

__global__ __launch_bounds__(256) void sp_reduce(
    const float4* __restrict__ feat4,
    const int* __restrict__ sorted_nid,
    const int* __restrict__ off,
    const int* __restrict__ bsum,
    const int* __restrict__ cnt,
    float4* __restrict__ out4)
{
    int seg  = blockIdx.x * 8 + (threadIdx.x >> 5);
    int lane = threadIdx.x & 31;
    if (seg >= N_SEG) return;

    int n   = cnt[seg];
    int beg = off[seg] + bsum[seg >> 10];
    int m   = (n < 32) ? n : 32;
    int myid = (lane < m) ? sorted_nid[beg + lane] : 0;

    float4 acc0 = make_float4(0.f, 0.f, 0.f, 0.f);
    float4 acc1 = make_float4(0.f, 0.f, 0.f, 0.f);

    if (m > 0) {
        int last = m - 1;
        for (int j0 = 0; j0 < m; j0 += 8) {
            int id[8];
#pragma unroll
            for (int k = 0; k < 8; ++k) {
                int jj = j0 + k;
                id[k] = __shfl(myid, (jj < last) ? jj : last, 32);
            }
            float4 b[8];
#pragma unroll
            for (int k = 0; k < 8; ++k)
                b[k] = feat4[(size_t)id[k] * 32 + lane];
#pragma unroll
            for (int k = 0; k < 8; ++k) {
                if (j0 + k < m) {
                    if (k & 1) {
                        acc1.x += b[k].x; acc1.y += b[k].y;
                        acc1.z += b[k].z; acc1.w += b[k].w;
                    } else {
                        acc0.x += b[k].x; acc0.y += b[k].y;
                        acc0.z += b[k].z; acc0.w += b[k].w;
                    }
                }
            }
        }
        for (int k = 32; k < n; ++k) {
            int nk = sorted_nid[beg + k];
            float4 a = feat4[(size_t)nk * 32 + lane];
            acc0.x += a.x; acc0.y += a.y; acc0.z += a.z; acc0.w += a.w;
        }
    }

    float inv = 1.0f / (float)((n > 0) ? n : 1);
    nt4 r;
    r.x = (acc0.x + acc1.x) * inv;
    r.y = (acc0.y + acc1.y) * inv;
    r.z = (acc0.z + acc1.z) * inv;
    r.w = (acc0.w + acc1.w) * inv;
    __builtin_nontemporal_store(
        r, reinterpret_cast<nt4*>(out4) + (size_t)seg * 32 + lane);
}

// ================= launch =================

extern "C" void kernel_launch(void* const* d_in, const int* in_sizes, int n_in,
                              void* d_out, int out_size, void* d_ws, size_t ws_size,
                              hipStream_t stream) {
    const float* feat = (const float*)d_in[0];
    const int*   nid  = (const int*)d_in[1];
    const int*   sid  = (const int*)d_in[2];
    const int n_edges = in_sizes[1];

    if (ws_size >= WS_NEED_H && n_edges > 0) {
        int* cursor  = NP_CUR(d_ws);
        int* ovfc    = NP_OVFC(d_ws);
        int2* ovf    = NP_OVF(d_ws);
        int* pairs   = NP_PAIRS(d_ws);
        unsigned int* feat16 = (unsigned int*)NP_F16(d_ws);

        int n8 = N_NODES * D_FEAT / 8;
        sp_cvt<<<(n8 + 255) / 256, 256, 0, stream>>>(feat, feat16, n8,
                                                     cursor, ovfc);
        int sb = (n_edges + EPB - 1) / EPB;
        sp_bucket_scatter<<<sb, CTH, 0, stream>>>(sid, nid, cursor, pairs,
                                                  ovfc, ovf, n_edges);
        sp_reduce_f<<<NB, CTH, 0, stream>>>((const ushort4*)feat16, pairs,
                                            cursor, ovfc, ovf,
                                            (float4*)d_out);
    } else {
        // fallback: verified fp32 rank path
        int* cnt    = RP_CNT(d_ws);
        int* off    = RP_OFF(d_ws);
        int* bsum   = RP_BSUM(d_ws);
        int* rank   = RP_RANK(d_ws);
        int* sorted = RP_SORTED(d_ws);
        int eb = (n_edges + 255) / 256;
        int rb = (N_SEG + 7) / 8;

        hipMemsetAsync(d_ws, 0, (size_t)(1u << 20), stream);
        sp_hist_rank<<<eb, 256, 0, stream>>>(sid, cnt, rank, n_edges);
        sp_scan_local<<<SCAN_BLOCKS, 256, 0, stream>>>(cnt, off, bsum);
        sp_scan_blocks<<<1, 256, 0, stream>>>(bsum);
        sp_reorder_rank<<<eb, 256, 0, stream>>>(nid, sid, off, bsum, rank,
                                                sorted, n_edges);
        sp_reduce<<<rb, 256, 0, stream>>>((const float4*)feat, sorted, off,
                                          bsum, cnt, (float4*)d_out);
    }
}

// Round 10
// 279.910 us; speedup vs baseline: 1.0521x; 1.0521x over previous
//
#include <hip/hip_runtime.h>
#include <hip/hip_fp16.h>

// SubgraphPooling: fused cvt+bucket-scatter, then fused bucket-sort/reduce.
// out[s,:] = mean over edges e with sid[e]==s of feat[nid[e],:]
// N_NODES=100000, D=128, E=2000000, N_SEG=250000
//
// R14 changes vs R13 (294us):
//  - cursor_g padded to one per 64B line (was 977 ints in 61 lines in one
//    4KB page -> per-line/per-channel atomic serialization, ~4K serialized
//    atomics per line). Now ~1000 lines across many L2 channels.
//  - cvt fused into the scatter kernel as extra blocks (scatter blocks
//    first so they schedule first; cvt blocks fill idle CU slots and
//    overlap with the scatter's atomic/LDS phases). Hides cvt's 13us.
//  - EPB back to 8192 (runs ~8.4 edges -> half the cursor atomics and
//    half the partial-line write fragmentation vs 4096).
//  - 3 stream ops: memset(64KB) + fused + reduce.

constexpr int N_NODES = 100000;
constexpr int D_FEAT  = 128;
constexpr int N_SEG   = 250000;

constexpr int BSHIFT     = 8;
constexpr int SEGS_PER_B = 1 << BSHIFT;                        // 256
constexpr int NB         = (N_SEG + SEGS_PER_B - 1) >> BSHIFT; // 977
constexpr int NB_PAD     = 1024;
constexpr int EPB        = 8192;                               // edges/block
constexpr int CTH        = 512;
constexpr int CAP_B      = 4096;                               // slots/bucket
constexpr int NID_BITS   = 17;                                 // 100000 < 2^17
constexpr int NID_MASK   = (1 << NID_BITS) - 1;
constexpr int OVF_CAP    = 262144;
constexpr int CUR_STRIDE = 16;                                 // 64B per bucket

// ---- workspace layout ----
// [0, 62528)       cursor[NB*16]       (zeroed, padded: 1 per 64B line)
// [64512, 64516)   ovf_cnt             (zeroed)
// [1MB, 1MB+15.3MB) pairs  int[NB*CAP_B]
// [18MB, 20MB)     ovf    int2[OVF_CAP]
// [20MB, +25.6MB)  feat16
#define NP_CUR(ws)    ((int*)((char*)(ws) + 0))
#define NP_OVFC(ws)   ((int*)((char*)(ws) + 64512))
#define NP_PAIRS(ws)  ((int*)((char*)(ws) + (1u<<20)))
#define NP_OVF(ws)    ((int2*)((char*)(ws) + (18u<<20)))
#define NP_F16(ws)    ((char*)(ws) + (20u<<20))
constexpr size_t FP16_BYTES = (size_t)N_NODES * D_FEAT * 2;          // 25.6 MB
constexpr size_t WS_NEED_H  = (size_t)(20u << 20) + FP16_BYTES;      // ~46.6 MB

// ---- fallback (verified fp32 rank path) layout ----
#define RP_CNT(ws)     ((int*)((char*)(ws) + 0))
#define RP_OFF(ws)     ((int*)((char*)(ws) + (1u<<20)))
#define RP_BSUM(ws)    ((int*)((char*)(ws) + (2u<<20)))
#define RP_RANK(ws)    ((int*)((char*)(ws) + (4u<<20)))
#define RP_SORTED(ws)  ((int*)((char*)(ws) + (12u<<20)))
constexpr int SCAN_CHUNK  = 1024;
constexpr int SCAN_BLOCKS = (N_SEG + SCAN_CHUNK - 1) / SCAN_CHUNK;  // 245

typedef float nt4 __attribute__((ext_vector_type(4)));
typedef unsigned int ntu4 __attribute__((ext_vector_type(4)));

// ========== fused cvt + bucket scatter (independent roles, one kernel) ====

__global__ __launch_bounds__(CTH) void sp_fused_cvt_scatter(
    const float* __restrict__ feat, unsigned int* __restrict__ feat16,
    int n8,
    const int* __restrict__ sid, const int* __restrict__ nid,
    int* __restrict__ cursor_g, int* __restrict__ pairs,
    int* __restrict__ ovf_cnt, int2* __restrict__ ovf, int n, int sb)
{
    __shared__ int hist[NB_PAD];               // counts -> LDS cursors (4KB)
    __shared__ int dstb[NB_PAD];               // global base - local off (4KB)
    __shared__ int lpair[EPB];                 // packed (slow<<17|nid), 32KB
    __shared__ unsigned short lbuck[EPB];      // bucket per slot, 16KB
    __shared__ int sh[CTH];                    // 2KB
    int tid = threadIdx.x;

    if ((int)blockIdx.x >= sb) {
        // ---- cvt role: feat fp32 -> fp16 table, 8 floats/thread ----
        int i = (blockIdx.x - sb) * CTH + tid;
        if (i < n8) {
            const nt4* in4 = (const nt4*)feat;
            nt4 v0 = __builtin_nontemporal_load(&in4[2 * i + 0]);
            nt4 v1 = __builtin_nontemporal_load(&in4[2 * i + 1]);
            __half2 h0 = __floats2half2_rn(v0.x, v0.y);
            __half2 h1 = __floats2half2_rn(v0.z, v0.w);
            __half2 h2 = __floats2half2_rn(v1.x, v1.y);
            __half2 h3 = __floats2half2_rn(v1.z, v1.w);
            ntu4 o;
            o.x = *(const unsigned int*)&h0;
            o.y = *(const unsigned int*)&h1;
            o.z = *(const unsigned int*)&h2;
            o.w = *(const unsigned int*)&h3;
            __builtin_nontemporal_store(o, (ntu4*)feat16 + i);
        }
        return;
    }

    // ---- scatter role ----
    int e0 = blockIdx.x * EPB;
    int m  = min(EPB, n - e0);

    for (int i = tid; i < NB_PAD; i += CTH) hist[i] = 0;
    __syncthreads();
    for (int i = tid; i < m; i += CTH)
        atomicAdd(&hist[sid[e0 + i] >> BSHIFT], 1);
    __syncthreads();

    // exclusive scan of 1024 bucket counts (2/thread over 512 threads)
    int b0 = 2 * tid, b1 = 2 * tid + 1;
    int h0 = hist[b0], h1 = hist[b1];
    sh[tid] = h0 + h1;
    __syncthreads();
    for (int o = 1; o < CTH; o <<= 1) {
        int t = (tid >= o) ? sh[tid - o] : 0;
        __syncthreads();
        sh[tid] += t;
        __syncthreads();
    }
    int excl = (tid > 0) ? sh[tid - 1] : 0;
    __syncthreads();                           // all reads of hist done
    hist[b0] = excl;                           // LDS scatter cursors
    hist[b1] = excl + h0;
    // allocate this block's run in each bucket's padded region
    int a0 = (b0 < NB && h0 > 0) ? atomicAdd(&cursor_g[b0 * CUR_STRIDE], h0) : 0;
    int a1 = (b1 < NB && h1 > 0) ? atomicAdd(&cursor_g[b1 * CUR_STRIDE], h1) : 0;
    dstb[b0] = a0 - excl;
    dstb[b1] = a1 - (excl + h0);
    __syncthreads();

    // group into LDS by bucket
    for (int i = tid; i < m; i += CTH) {
        int s = sid[e0 + i], v = nid[e0 + i];
        int b = s >> BSHIFT;
        int r = atomicAdd(&hist[b], 1);
        lpair[r] = ((s & (SEGS_PER_B - 1)) << NID_BITS) | v;
        lbuck[r] = (unsigned short)b;
    }
    __syncthreads();

    // write out: each bucket's run lands contiguously in its padded region
    for (int i = tid; i < m; i += CTH) {
        int b  = lbuck[i];
        int p  = dstb[b] + i;                  // position within bucket
        int pk = lpair[i];
        if (p < CAP_B) {
            pairs[b * CAP_B + p] = pk;
        } else {                               // far-tail overflow: exact list
            int o = atomicAdd(ovf_cnt, 1);
            if (o < OVF_CAP)
                ovf[o] = make_int2((b << BSHIFT) | (pk >> NID_BITS),
                                   pk & NID_MASK);
        }
    }
}

// ================= fp16 helpers =================

__device__ __forceinline__ float2 h2f(unsigned short lo, unsigned short hi)
{
    __half2 h = __halves2half2(__ushort_as_half(lo), __ushort_as_half(hi));
    return __half22float2(h);
}

__device__ __forceinline__ void acc_h(float4& acc, const ushort4& b)
{
    float2 f01 = h2f(b.x, b.y);
    float2 f23 = h2f(b.z, b.w);
    acc.x += f01.x; acc.y += f01.y; acc.z += f23.x; acc.w += f23.y;
}

// ============ fused bucket-sort + reduce (one block per bucket) ==========

__global__ __launch_bounds__(CTH) void sp_reduce_f(
    const ushort4* __restrict__ feat16,    // [N_NODES][32] ushort4
    const int* __restrict__ pairs,
    const int* __restrict__ cursor_g,
    const int* __restrict__ ovf_cnt,
    const int2* __restrict__ ovf,
    float4* __restrict__ out4)             // [N_SEG][32] float4
{
    __shared__ int cnt[SEGS_PER_B];
    __shared__ int beg[SEGS_PER_B];
    __shared__ int cur[SEGS_PER_B];
    __shared__ int sh[SEGS_PER_B];
    __shared__ int lp[CAP_B];              // 16KB staged pairs (1 global pass)
    __shared__ int snid[CAP_B];            // 16KB segment-sorted nids
    int B = blockIdx.x, tid = threadIdx.x;
    int total = cursor_g[B * CUR_STRIDE];
    int mc = min(total, CAP_B);
    const int* bp = pairs + (size_t)B * CAP_B;

    if (tid < SEGS_PER_B) cnt[tid] = 0;
    __syncthreads();
    for (int i = tid; i < mc; i += CTH) {
        int p = bp[i];
        lp[i] = p;
        atomicAdd(&cnt[(p >> NID_BITS) & (SEGS_PER_B - 1)], 1);
    }
    __syncthreads();

    int c = (tid < SEGS_PER_B) ? cnt[tid] : 0;
    if (tid < SEGS_PER_B) sh[tid] = c;
    __syncthreads();
    for (int o = 1; o < SEGS_PER_B; o <<= 1) {
        int t = (tid < SEGS_PER_B && tid >= o) ? sh[tid - o] : 0;
        __syncthreads();
        if (tid < SEGS_PER_B) sh[tid] += t;
        __syncthreads();
    }
    if (tid < SEGS_PER_B) { beg[tid] = sh[tid] - c; cur[tid] = sh[tid] - c; }
    __syncthreads();

    for (int i = tid; i < mc; i += CTH) {
        int p  = lp[i];
        int sl = (p >> NID_BITS) & (SEGS_PER_B - 1);
        int r  = atomicAdd(&cur[sl], 1);
        snid[r] = p & NID_MASK;
    }
    __syncthreads();

    int ovfB = total - mc;                 // >0 -> this bucket overflowed
    int ovn  = (ovfB > 0) ? min(*ovf_cnt, OVF_CAP) : 0;

    int hw = tid >> 5, lane = tid & 31;    // 16 half-waves x 16 segments
    for (int t = 0; t < SEGS_PER_B / 16; ++t) {
        int sl = hw * (SEGS_PER_B / 16) + t;
        int s  = (B << BSHIFT) + sl;
        if (s >= N_SEG) continue;
        int nst = cnt[sl], bg = beg[sl];
        int m2  = (nst < 32) ? nst : 32;
        int myid = (lane < m2) ? snid[bg + lane] : 0;

        float4 acc0 = make_float4(0.f, 0.f, 0.f, 0.f);
        float4 acc1 = make_float4(0.f, 0.f, 0.f, 0.f);
        if (m2 > 0) {
            int last = m2 - 1;
            for (int j0 = 0; j0 < m2; j0 += 8) {
                int id[8];
#pragma unroll
                for (int k = 0; k < 8; ++k) {
                    int jj = j0 + k;
                    id[k] = __shfl(myid, (jj < last) ? jj : last, 32);
                }
                ushort4 b[8];
#pragma unroll
                for (int k = 0; k < 8; ++k)
                    b[k] = feat16[(size_t)id[k] * 32 + lane];
#pragma unroll
                for (int k = 0; k < 8; ++k) {
                    if (j0 + k < m2) {
                        if (k & 1) acc_h(acc1, b[k]);
                        else       acc_h(acc0, b[k]);
                    }
                }
            }
            for (int k = 32; k < nst; ++k)          // n>32: LDS-resident tail
                acc_h(acc0, feat16[(size_t)snid[bg + k] * 32 + lane]);
        }
        int ntrue = nst;
        if (ovfB > 0) {                             // exact overflow drain
            for (int k = 0; k < ovn; ++k) {
                int2 e = ovf[k];
                if (e.x == s) {
                    acc_h(acc0, feat16[(size_t)e.y * 32 + lane]);
                    ++ntrue;
                }
            }
        }
        float inv = 1.0f / (float)((ntrue > 0) ? ntrue : 1);
        nt4 r;
        r.x = (acc0.x + acc1.x) * inv;
        r.y = (acc0.y + acc1.y) * inv;
        r.z = (acc0.z + acc1.z) * inv;
        r.w = (acc0.w + acc1.w) * inv;
        __builtin_nontemporal_store(
            r, reinterpret_cast<nt4*>(out4) + (size_t)s * 32 + lane);
    }
}

// ================= fallback path (verified fp32 rank path) ===============

__global__ __launch_bounds__(256) void sp_hist_rank(
    const int* __restrict__ sid, int* __restrict__ cnt,
    int* __restrict__ rank, int n)
{
    int i = blockIdx.x * blockDim.x + threadIdx.x;
    if (i >= n) return;
    int s = sid[i];
    rank[i] = atomicAdd(&cnt[s], 1);
}

__global__ __launch_bounds__(256) void sp_scan_local(
    const int* __restrict__ cnt, int* __restrict__ off, int* __restrict__ bsum)
{
    __shared__ int sh[256];
    int tid  = threadIdx.x;
    int base = blockIdx.x * SCAN_CHUNK + tid * 4;
    int v0 = (base + 0 < N_SEG) ? cnt[base + 0] : 0;
    int v1 = (base + 1 < N_SEG) ? cnt[base + 1] : 0;
    int v2 = (base + 2 < N_SEG) ? cnt[base + 2] : 0;
    int v3 = (base + 3 < N_SEG) ? cnt[base + 3] : 0;
    sh[tid] = v0 + v1 + v2 + v3;
    __syncthreads();
    for (int o = 1; o < 256; o <<= 1) {
        int t = (tid >= o) ? sh[tid - o] : 0;
        __syncthreads();
        sh[tid] += t;
        __syncthreads();
    }
    int excl = (tid > 0) ? sh[tid - 1] : 0;
    if (base + 0 < N_SEG) off[base + 0] = excl;
    if (base + 1 < N_SEG) off[base + 1] = excl + v0;
    if (base + 2 < N_SEG) off[base + 2] = excl + v0 + v1;
    if (base + 3 < N_SEG) off[base + 3] = excl + v0 + v1 + v2;
    if (tid == 255) bsum[blockIdx.x] = sh[255];
}

__global__ __launch_bounds__(256) void sp_scan_blocks(int* __restrict__ bsum)
{
    __shared__ int sh[256];
    int tid = threadIdx.x;
    int v = (tid < SCAN_BLOCKS) ? bsum[tid] : 0;
    sh[tid] = v;
    __syncthreads();
    for (int o = 1; o < 256; o <<= 1) {
        int t = (tid >= o) ? sh[tid - o] : 0;
        __syncthreads();
        sh[tid] += t;
        __syncthreads();
    }
    if (tid < SCAN_BLOCKS) bsum[tid] = sh[tid] - v;
}

__global__ __launch_bounds__(256) void sp_reorder_rank(
    const int* __restrict__ nid, const int* __restrict__ sid,
    const int* __restrict__ off, const int* __restrict__ bsum,
    const int* __restrict__ rank, int* __restrict__ sorted_nid, int n)
{
    int i = blockIdx.x * blockDim.x + threadIdx.x;
    if (i >= n) return;
    int s = sid[i];
    sorted_nid[off[s] + bsum[s >> 10] + rank[i]] = nid[i];
}

__global__ __launch_bounds__(256) void sp_reduce(
    const float4* __restrict__ feat4,
    const int* __restrict__ sorted_nid,
    const int* __restrict__ off,
    const int* __restrict__ bsum,
    const int* __restrict__ cnt,
    float4* __restrict__ out4)
{
    int seg  = blockIdx.x * 8 + (threadIdx.x >> 5);
    int lane = threadIdx.x & 31;
    if (seg >= N_SEG) return;

    int n   = cnt[seg];
    int beg = off[seg] + bsum[seg >> 10];
    int m   = (n < 32) ? n : 32;
    int myid = (lane < m) ? sorted_nid[beg + lane] : 0;

    float4 acc0 = make_float4(0.f, 0.f, 0.f, 0.f);
    float4 acc1 = make_float4(0.f, 0.f, 0.f, 0.f);

    if (m > 0) {
        int last = m - 1;
        for (int j0 = 0; j0 < m; j0 += 8) {
            int id[8];
#pragma unroll
            for (int k = 0; k < 8; ++k) {
                int jj = j0 + k;
                id[k] = __shfl(myid, (jj < last) ? jj : last, 32);
            }
            float4 b[8];
#pragma unroll
            for (int k = 0; k < 8; ++k)
                b[k] = feat4[(size_t)id[k] * 32 + lane];
#pragma unroll
            for (int k = 0; k < 8; ++k) {
                if (j0 + k < m) {
                    if (k & 1) {
                        acc1.x += b[k].x; acc1.y += b[k].y;
                        acc1.z += b[k].z; acc1.w += b[k].w;
                    } else {
                        acc0.x += b[k].x; acc0.y += b[k].y;
                        acc0.z += b[k].z; acc0.w += b[k].w;
                    }
                }
            }
        }
        for (int k = 32; k < n; ++k) {
            int nk = sorted_nid[beg + k];
            float4 a = feat4[(size_t)nk * 32 + lane];
            acc0.x += a.x; acc0.y += a.y; acc0.z += a.z; acc0.w += a.w;
        }
    }

    float inv = 1.0f / (float)((n > 0) ? n : 1);
    nt4 r;
    r.x = (acc0.x + acc1.x) * inv;
    r.y = (acc0.y + acc1.y) * inv;
    r.z = (acc0.z + acc1.z) * inv;
    r.w = (acc0.w + acc1.w) * inv;
    __builtin_nontemporal_store(
        r, reinterpret_cast<nt4*>(out4) + (size_t)seg * 32 + lane);
}

// ================= launch =================

extern "C" void kernel_launch(void* const* d_in, const int* in_sizes, int n_in,
                              void* d_out, int out_size, void* d_ws, size_t ws_size,
                              hipStream_t stream) {
    const float* feat = (const float*)d_in[0];
    const int*   nid  = (const int*)d_in[1];
    const int*   sid  = (const int*)d_in[2];
    const int n_edges = in_sizes[1];

    if (ws_size >= WS_NEED_H && n_edges > 0) {
        int* cursor  = NP_CUR(d_ws);
        int* ovfc    = NP_OVFC(d_ws);
        int2* ovf    = NP_OVF(d_ws);
        int* pairs   = NP_PAIRS(d_ws);
        unsigned int* feat16 = (unsigned int*)NP_F16(d_ws);

        hipMemsetAsync(d_ws, 0, 65536, stream);        // padded cursors + ovfc
        int n8 = N_NODES * D_FEAT / 8;                  // 1.6M float8 elems
        int sb  = (n_edges + EPB - 1) / EPB;            // scatter blocks
        int cvb = (n8 + CTH - 1) / CTH;                 // cvt blocks
        sp_fused_cvt_scatter<<<sb + cvb, CTH, 0, stream>>>(
            feat, feat16, n8, sid, nid, cursor, pairs, ovfc, ovf,
            n_edges, sb);
        sp_reduce_f<<<NB, CTH, 0, stream>>>((const ushort4*)feat16, pairs,
                                            cursor, ovfc, ovf,
                                            (float4*)d_out);
    } else {
        // fallback: verified fp32 rank path
        int* cnt    = RP_CNT(d_ws);
        int* off    = RP_OFF(d_ws);
        int* bsum   = RP_BSUM(d_ws);
        int* rank   = RP_RANK(d_ws);
        int* sorted = RP_SORTED(d_ws);
        int eb = (n_edges + 255) / 256;
        int rb = (N_SEG + 7) / 8;

        hipMemsetAsync(d_ws, 0, (size_t)(1u << 20), stream);
        sp_hist_rank<<<eb, 256, 0, stream>>>(sid, cnt, rank, n_edges);
        sp_scan_local<<<SCAN_BLOCKS, 256, 0, stream>>>(cnt, off, bsum);
        sp_scan_blocks<<<1, 256, 0, stream>>>(bsum);
        sp_reorder_rank<<<eb, 256, 0, stream>>>(nid, sid, off, bsum, rank,
                                                sorted, n_edges);
        sp_reduce<<<rb, 256, 0, stream>>>((const float4*)feat, sorted, off,
                                          bsum, cnt, (float4*)d_out);
    }
}